// Round 7
// baseline (272.997 us; speedup 1.0000x reference)
//
#include <hip/hip_runtime.h>

typedef __bf16 bf16x8 __attribute__((ext_vector_type(8)));
typedef __bf16 bf16x4 __attribute__((ext_vector_type(4)));
typedef _Float16 half4 __attribute__((ext_vector_type(4)));
typedef _Float16 half8 __attribute__((ext_vector_type(8)));
typedef float f32x4 __attribute__((ext_vector_type(4)));

#define MFMA_BF16(a, b, c) __builtin_amdgcn_mfma_f32_16x16x32_bf16(a, b, c, 0, 0, 0)
#define MFMA_F16K32(a, b, c) __builtin_amdgcn_mfma_f32_16x16x32_f16(a, b, c, 0, 0, 0)
#define MFMA_F16K16(a, b, c) __builtin_amdgcn_mfma_f32_16x16x16f16(a, b, c, 0, 0, 0)
#define EXP2F(x) __builtin_amdgcn_exp2f(x)

constexpr int NSEQ = 2048, DIM = 1024;
constexpr int MROWS = 4096;
constexpr float QSCALE = 11.5415603271f;  // 8 * log2(e)

__device__ __forceinline__ void split_bf16(float x, __bf16& h, __bf16& l) {
  h = (__bf16)x;
  l = (__bf16)(x - (float)h);
}

__device__ __forceinline__ void ld_lds16(void* lds, const void* g) {
  __builtin_amdgcn_global_load_lds(
      (const __attribute__((address_space(1))) void*)g,
      (__attribute__((address_space(3))) void*)lds, 16, 0, 0);
}

// ---------------------------------------------------------------------------
// Merged prep: blocks 0..1023 transpose weights (64x64 f32 tiles);
// blocks 1024..3071 split x into bf16 hi/lo.
// ---------------------------------------------------------------------------
__global__ __launch_bounds__(256) void prep(
    const float* __restrict__ w_q, const float* __restrict__ w_vk,
    const float* __restrict__ w_out, const float* __restrict__ x,
    __bf16* __restrict__ WTh, __bf16* __restrict__ WTl,
    _Float16* __restrict__ WoT, __bf16* __restrict__ xh,
    __bf16* __restrict__ xl) {
  const int bid = blockIdx.x;
  const int t = threadIdx.x;
  if (bid >= 1024) {  // ---- split_x ----
    const size_t i = ((size_t)(bid - 1024) * 256 + t) * 8;
    float4 a = *(const float4*)(x + i), b2 = *(const float4*)(x + i + 4);
    float v[8] = {a.x, a.y, a.z, a.w, b2.x, b2.y, b2.z, b2.w};
    bf16x8 h, l;
#pragma unroll
    for (int j = 0; j < 8; ++j) {
      __bf16 hh, ll;
      split_bf16(v[j], hh, ll);
      h[j] = hh; l[j] = ll;
    }
    *(bf16x8*)(xh + i) = h;
    *(bf16x8*)(xl + i) = l;
    return;
  }
  // ---- weight transpose ----
  __shared__ float T[64][65];
  const int bx = bid & 63, k0 = (bid >> 6) * 64;
  const float* src;
  int srcN, n0, dstrow, mode;
  float scale;
  if (bx < 16) {
    src = w_q; srcN = 1024; n0 = bx * 64; dstrow = n0; scale = QSCALE; mode = 0;
  } else if (bx < 48) {
    src = w_vk; srcN = 2048; n0 = (bx - 16) * 64; dstrow = 1024 + n0;
    scale = 1.0f; mode = 0;
  } else {
    src = w_out; srcN = 1024; n0 = (bx - 48) * 64; dstrow = n0;
    scale = 1.0f; mode = 1;
  }
  {
    const int r = t >> 2, c4 = (t & 3) * 16;
    const float* s = src + (size_t)(k0 + r) * srcN + n0 + c4;
    float4 v0 = ((const float4*)s)[0], v1 = ((const float4*)s)[1],
           v2 = ((const float4*)s)[2], v3 = ((const float4*)s)[3];
    *(float4*)&T[r][c4 + 0] = v0;  *(float4*)&T[r][c4 + 4] = v1;
    *(float4*)&T[r][c4 + 8] = v2;  *(float4*)&T[r][c4 + 12] = v3;
  }
  __syncthreads();
  const int rn = t >> 2, kc = (t & 3) * 16;
  if (mode == 0) {
    bf16x8 hv[2], lv[2];
#pragma unroll
    for (int half = 0; half < 2; ++half)
#pragma unroll
      for (int j = 0; j < 8; ++j) {
        float v = T[kc + half * 8 + j][rn] * scale;
        __bf16 h, l;
        split_bf16(v, h, l);
        hv[half][j] = h; lv[half][j] = l;
      }
    __bf16* dh = WTh + (size_t)(dstrow + rn) * 1024 + k0 + kc;
    *(bf16x8*)dh = hv[0]; *(bf16x8*)(dh + 8) = hv[1];
    if (dstrow < 2048) {
      __bf16* dl = WTl + (size_t)(dstrow + rn) * 1024 + k0 + kc;
      *(bf16x8*)dl = lv[0]; *(bf16x8*)(dl + 8) = lv[1];
    }
  } else {
    half8 hv[2];
#pragma unroll
    for (int half = 0; half < 2; ++half)
#pragma unroll
      for (int j = 0; j < 8; ++j)
        hv[half][j] = (_Float16)T[kc + half * 8 + j][rn];
    _Float16* d = WoT + (size_t)(n0 + rn) * 1024 + k0 + kc;
    *(half8*)d = hv[0]; *(half8*)(d + 8) = hv[1];
  }
}

// ---------------------------------------------------------------------------
// Fused q/k/v projection (round-5 proj4: 32KB LDS, 3 blocks/CU, 2-barrier).
// kind 0: q -> qTh/qTl transposed; 1: k -> KH/KL; 2: v -> VT fp16.
// ---------------------------------------------------------------------------
__global__ __launch_bounds__(256, 3) void proj4(
    const __bf16* __restrict__ xh, const __bf16* __restrict__ xl,
    const __bf16* __restrict__ WTh, const __bf16* __restrict__ WTl,
    __bf16* __restrict__ qTh, __bf16* __restrict__ qTl,
    __bf16* __restrict__ KH, __bf16* __restrict__ KL,
    _Float16* __restrict__ VT) {
  __shared__ __align__(16) __bf16 Xhs[128 * 32], Xls[128 * 32];
  __shared__ __align__(16) __bf16 Bhs[128 * 32], Bls[128 * 32];
  const int t = threadIdx.x;
  const int lane = t & 63, wave = t >> 6, quad = lane >> 4, lq = lane & 15;
  const int bn = blockIdx.x * 128, bm = blockIdx.y * 128;
  const int kind = bn >> 10;
  const int wm = (wave >> 1) * 64, wn = (wave & 1) * 64;

  const int srow = lane >> 2;                  // 0..15
  const int schk = (lane & 3) ^ (srow & 3);    // 16B chunk
  const __bf16* xh_g = xh + (size_t)(bm + wave * 32 + srow) * DIM + schk * 8;
  const __bf16* xl_g = xl + (size_t)(bm + wave * 32 + srow) * DIM + schk * 8;
  const __bf16* bh_g = WTh + (size_t)(bn + wave * 32 + srow) * DIM + schk * 8;
  const __bf16* bl_g = WTl + (size_t)(bn + wave * 32 + srow) * DIM + schk * 8;
  const int sbase = (wave * 32) * 32;

  const int swz = (quad ^ (lq & 3)) * 8;

  f32x4 acc[4][4];
#pragma unroll
  for (int i = 0; i < 4; ++i)
#pragma unroll
    for (int j = 0; j < 4; ++j) acc[i][j] = (f32x4){0.f, 0.f, 0.f, 0.f};

  for (int k0 = 0; k0 < DIM; k0 += 32) {
    ld_lds16(Xhs + sbase, xh_g + k0);
    ld_lds16(Xhs + sbase + 512, xh_g + k0 + 16 * DIM);
    ld_lds16(Xls + sbase, xl_g + k0);
    ld_lds16(Xls + sbase + 512, xl_g + k0 + 16 * DIM);
    ld_lds16(Bhs + sbase, bh_g + k0);
    ld_lds16(Bhs + sbase + 512, bh_g + k0 + 16 * DIM);
    if (kind < 2) {
      ld_lds16(Bls + sbase, bl_g + k0);
      ld_lds16(Bls + sbase + 512, bl_g + k0 + 16 * DIM);
    }
    __syncthreads();

    bf16x8 ah[4], al[4];
#pragma unroll
    for (int i = 0; i < 4; ++i) {
      const int off = (wm + i * 16 + lq) * 32 + swz;
      ah[i] = *(const bf16x8*)&Xhs[off];
      al[i] = *(const bf16x8*)&Xls[off];
    }
#pragma unroll
    for (int j = 0; j < 4; ++j) {
      const int boff = (wn + j * 16 + lq) * 32 + swz;
      bf16x8 bh = *(const bf16x8*)&Bhs[boff];
      if (kind < 2) {
        bf16x8 bl = *(const bf16x8*)&Bls[boff];
#pragma unroll
        for (int i = 0; i < 4; ++i) {
          acc[i][j] = MFMA_BF16(ah[i], bh, acc[i][j]);
          acc[i][j] = MFMA_BF16(al[i], bh, acc[i][j]);
          acc[i][j] = MFMA_BF16(ah[i], bl, acc[i][j]);
        }
      } else {
#pragma unroll
        for (int i = 0; i < 4; ++i) {
          acc[i][j] = MFMA_BF16(ah[i], bh, acc[i][j]);
          acc[i][j] = MFMA_BF16(al[i], bh, acc[i][j]);
        }
      }
    }
    __syncthreads();
  }

  if (kind == 0) {  // q transposed [col][token], hi/lo, 8B vector stores
#pragma unroll
    for (int i = 0; i < 4; ++i)
#pragma unroll
      for (int j = 0; j < 4; ++j) {
        const int col = bn + wn + j * 16 + lq;
        const int token = bm + wm + i * 16 + quad * 4;
        bf16x4 h4, l4;
#pragma unroll
        for (int r = 0; r < 4; ++r) {
          __bf16 h, l;
          split_bf16(acc[i][j][r], h, l);
          h4[r] = h; l4[r] = l;
        }
        *(bf16x4*)(qTh + (size_t)col * MROWS + token) = h4;
        *(bf16x4*)(qTl + (size_t)col * MROWS + token) = l4;
      }
  } else if (kind == 1) {
#pragma unroll
    for (int i = 0; i < 4; ++i)
#pragma unroll
      for (int j = 0; j < 4; ++j) {
        const int col = (bn - 1024) + wn + j * 16 + lq;
#pragma unroll
        for (int r = 0; r < 4; ++r) {
          const int row = bm + wm + i * 16 + quad * 4 + r;
          __bf16 h, l;
          split_bf16(acc[i][j][r], h, l);
          KH[(size_t)row * 1024 + col] = h;
          KL[(size_t)row * 1024 + col] = l;
        }
      }
  } else {  // v -> vT[b][h][d][n] fp16
#pragma unroll
    for (int i = 0; i < 4; ++i)
#pragma unroll
      for (int j = 0; j < 4; ++j) {
        const int c = (bn - 2048) + wn + j * 16 + lq;
        const int row0 = bm + wm + i * 16 + quad * 4;
        const int b = row0 >> 11, n = row0 & 2047;
        const int h = c >> 6, d = c & 63;
        half4 o;
#pragma unroll
        for (int r = 0; r < 4; ++r) o[r] = (_Float16)acc[i][j][r];
        *(half4*)(VT + ((size_t)(b * 16 + h) * 64 + d) * 2048 + n) = o;
      }
  }
}

// ---------------------------------------------------------------------------
// Key-split flash attention. Grid (16, 32, 2): z = key half (1024 keys).
// TI=128 (4 waves x 32 q-rows), TJ=64, single-buffer 24KB LDS -> 4 blocks/CU.
// Writes normalized partial O~ (f16) to pO[z][bh][tok][64] and (m,l) to ml.
// ---------------------------------------------------------------------------
__global__ __launch_bounds__(256, 4) void attn6(
    const __bf16* __restrict__ qTh, const __bf16* __restrict__ qTl,
    const __bf16* __restrict__ kh, const __bf16* __restrict__ kl,
    const _Float16* __restrict__ vT, _Float16* __restrict__ pO,
    float2* __restrict__ ml) {
  __shared__ __align__(16) char smem[24576];  // Kh 8K | Kl 8K | Vt 8K
  const int t = threadIdx.x;
  const int lane = t & 63, wave = t >> 6, quad = lane >> 4, lq = lane & 15;
  const int i0 = blockIdx.x * 128;
  const int bh = blockIdx.y, b = bh >> 4, head = bh & 15;
  const int z = blockIdx.z, kbase = z * 1024;
  const size_t rowbase = (size_t)b * NSEQ;

  // Q fragments (B-operand layout) from transposed q
  bf16x8 qfh[2][2], qfl[2][2];
#pragma unroll
  for (int qt = 0; qt < 2; ++qt) {
    const size_t tok = rowbase + i0 + wave * 32 + qt * 16 + lq;
#pragma unroll
    for (int hf = 0; hf < 2; ++hf)
#pragma unroll
      for (int jj = 0; jj < 8; ++jj) {
        const size_t c = (size_t)(head * 64 + hf * 32 + quad * 8 + jj) * MROWS + tok;
        qfh[qt][hf][jj] = qTh[c];
        qfl[qt][hf][jj] = qTl[c];
      }
  }

  f32x4 o[2][4];
#pragma unroll
  for (int qt = 0; qt < 2; ++qt)
#pragma unroll
    for (int dt = 0; dt < 4; ++dt) o[qt][dt] = (f32x4){0.f, 0.f, 0.f, 0.f};
  float mrun[2] = {-3.0e38f, -3.0e38f};
  float lrun[2] = {0.f, 0.f};

  const int srow = lane >> 3, schk = (lane & 7) ^ srow;
  const __bf16* khg =
      kh + (rowbase + kbase + wave * 16 + srow) * DIM + head * 64 + schk * 8;
  const __bf16* klg =
      kl + (rowbase + kbase + wave * 16 + srow) * DIM + head * 64 + schk * 8;
  const _Float16* vg =
      vT + ((size_t)bh * 64 + wave * 16 + srow) * NSEQ + kbase + schk * 8;
  const int wb = wave * 2048;

  char* Khb = smem;
  char* Klb = smem + 8192;
  char* Vtb = smem + 16384;
  const __bf16* Khs = (const __bf16*)Khb;
  const __bf16* Kls = (const __bf16*)Klb;
  const _Float16* Vts = (const _Float16*)Vtb;

  const int swzK0 = (quad ^ (lq & 7)) * 8;
  const int swzK1 = ((quad + 4) ^ (lq & 7)) * 8;

  for (int j0 = 0; j0 < 1024; j0 += 64) {
    ld_lds16(Khb + wb,        khg);
    ld_lds16(Khb + wb + 1024, khg + 8 * DIM);
    ld_lds16(Klb + wb,        klg);
    ld_lds16(Klb + wb + 1024, klg + 8 * DIM);
    ld_lds16(Vtb + wb,        vg);
    ld_lds16(Vtb + wb + 1024, vg + 8 * NSEQ);
    khg += (size_t)64 * DIM; klg += (size_t)64 * DIM; vg += 64;
    __syncthreads();

    // S^T = K.Q^T (hi/lo 3-product)
    f32x4 s[2][4];
#pragma unroll
    for (int nt = 0; nt < 4; ++nt) {
      const int roff = (nt * 16 + lq) * 64;
      bf16x8 k0f = *(const bf16x8*)&Khs[roff + swzK0];
      bf16x8 k1f = *(const bf16x8*)&Khs[roff + swzK1];
      bf16x8 l0f = *(const bf16x8*)&Kls[roff + swzK0];
      bf16x8 l1f = *(const bf16x8*)&Kls[roff + swzK1];
#pragma unroll
      for (int qt = 0; qt < 2; ++qt) {
        f32x4 sv = (f32x4){0.f, 0.f, 0.f, 0.f};
        sv = MFMA_BF16(k0f, qfh[qt][0], sv);
        sv = MFMA_BF16(k1f, qfh[qt][1], sv);
        sv = MFMA_BF16(k0f, qfl[qt][0], sv);
        sv = MFMA_BF16(k1f, qfl[qt][1], sv);
        sv = MFMA_BF16(l0f, qfh[qt][0], sv);
        sv = MFMA_BF16(l1f, qfh[qt][1], sv);
        s[qt][nt] = sv;
      }
    }

    // online softmax (rows lane-resident; 2 shuffles per reduction)
    half4 pb[2][4];
#pragma unroll
    for (int qt = 0; qt < 2; ++qt) {
      float mx = s[qt][0][0];
#pragma unroll
      for (int nt = 0; nt < 4; ++nt)
#pragma unroll
        for (int r = 0; r < 4; ++r) mx = fmaxf(mx, s[qt][nt][r]);
      mx = fmaxf(mx, __shfl_xor(mx, 16));
      mx = fmaxf(mx, __shfl_xor(mx, 32));
      const float mn = fmaxf(mrun[qt], mx);
      const float alpha = EXP2F(mrun[qt] - mn);
      mrun[qt] = mn;
      float rs = 0.f;
#pragma unroll
      for (int nt = 0; nt < 4; ++nt)
#pragma unroll
        for (int r = 0; r < 4; ++r) {
          float p = EXP2F(s[qt][nt][r] - mn);
          rs += p;
          pb[qt][nt][r] = (_Float16)p;
        }
      rs += __shfl_xor(rs, 16);
      rs += __shfl_xor(rs, 32);
      lrun[qt] = lrun[qt] * alpha + rs;
#pragma unroll
      for (int dt = 0; dt < 4; ++dt) o[qt][dt] *= alpha;
    }

    // O^T += V^T . P^T
#pragma unroll
    for (int dt = 0; dt < 4; ++dt) {
      const int vrow = (dt * 16 + lq) * 64;
#pragma unroll
      for (int nt = 0; nt < 4; ++nt) {
        const int chk = (nt * 2 + (quad >> 1)) ^ (lq & 7);
        half4 va = *(const half4*)&Vts[vrow + chk * 8 + (quad & 1) * 4];
        o[0][dt] = MFMA_F16K16(va, pb[0][nt], o[0][dt]);
        o[1][dt] = MFMA_F16K16(va, pb[1][nt], o[1][dt]);
      }
    }
    __syncthreads();
  }

  // epilogue: normalized partial O~ -> LDS transpose -> 16B stores; (m,l) out
  _Float16* Ots = (_Float16*)smem;
#pragma unroll
  for (int qt = 0; qt < 2; ++qt) {
    const float inv = 1.0f / lrun[qt];
#pragma unroll
    for (int dt = 0; dt < 4; ++dt)
#pragma unroll
      for (int r = 0; r < 4; ++r)
        Ots[(wave * 32 + qt * 16 + lq) * 80 + dt * 16 + quad * 4 + r] =
            (_Float16)(o[qt][dt][r] * inv);
  }
  if (quad == 0) {  // after shfl(16,32) reductions m,l are quad-uniform
#pragma unroll
    for (int qt = 0; qt < 2; ++qt) {
      const size_t idx =
          ((size_t)z * 32 + bh) * 2048 + i0 + wave * 32 + qt * 16 + lq;
      ml[idx] = (float2){mrun[qt], lrun[qt]};
    }
  }
  __syncthreads();
  {
    const int row = t >> 1, hf = t & 1;  // row 0..127, 32 f16 per thread
    const _Float16* src = &Ots[row * 80 + hf * 32];
    half8 o0 = ((const half8*)src)[0], o1 = ((const half8*)src)[1],
          o2 = ((const half8*)src)[2], o3 = ((const half8*)src)[3];
    _Float16* dst = pO + (((size_t)z * 32 + bh) * 2048 + i0 + row) * 64 + hf * 32;
    ((half8*)dst)[0] = o0; ((half8*)dst)[1] = o1;
    ((half8*)dst)[2] = o2; ((half8*)dst)[3] = o3;
  }
}

// ---------------------------------------------------------------------------
// Combine the two key-half partials into ho (fp16 [4096][1024]).
// ---------------------------------------------------------------------------
__global__ __launch_bounds__(256) void combine(
    const _Float16* __restrict__ pO, const float2* __restrict__ ml,
    _Float16* __restrict__ ho) {
  const int gid = blockIdx.x * 256 + threadIdx.x;  // 0..524287
  const int bh = gid >> 14;                        // 16384 per (b,h)
  const int rem = gid & 16383;
  const int tok = rem >> 3;
  const int dg = (rem & 7) * 8;
  const size_t base1 = (size_t)bh * 2048 + tok;
  const size_t base2 = ((size_t)32 + bh) * 2048 + tok;
  half8 o1 = *(const half8*)(pO + base1 * 64 + dg);
  half8 o2 = *(const half8*)(pO + base2 * 64 + dg);
  const float2 s1 = ml[base1], s2 = ml[base2];
  const float M = fmaxf(s1.x, s2.x);
  float w1 = s1.y * EXP2F(s1.x - M);
  float w2 = s2.y * EXP2F(s2.x - M);
  const float inv = 1.0f / (w1 + w2);
  w1 *= inv; w2 *= inv;
  half8 r;
#pragma unroll
  for (int j = 0; j < 8; ++j)
    r[j] = (_Float16)(w1 * (float)o1[j] + w2 * (float)o2[j]);
  const int b = bh >> 4, h = bh & 15;
  *(half8*)(ho + ((size_t)(b * 2048 + tok)) * 1024 + h * 64 + dg) = r;
}

// ---------------------------------------------------------------------------
// out = ho(fp16) @ w_out — double-buffered, one barrier per K-iter.
// ---------------------------------------------------------------------------
__global__ __launch_bounds__(256, 4) void gemm_out(
    const _Float16* __restrict__ A, const _Float16* __restrict__ BT,
    float* __restrict__ C) {
  __shared__ __align__(16) char smem[24576];  // 2 bufs: A 4KB | B 8KB
  const int t = threadIdx.x;
  const int lane = t & 63, wave = t >> 6, quad = lane >> 4, lq = lane & 15;
  const int bn = blockIdx.x * 128, bm = blockIdx.y * 64;
  const int wm = (wave >> 1) * 32, wn = (wave & 1) * 64;

  const int bco = (lane & 7) ^ (lane >> 3);
  const int brow = 2 * (lane >> 3) + (bco >> 2);
  const int bcc = bco & 3;
  const _Float16* ag = A + (size_t)(bm + wave * 16 + brow) * DIM + bcc * 8;
  const _Float16* bg = BT + (size_t)(bn + wave * 32 + brow) * DIM + bcc * 8;
  const int swzB = ((((lq & 1) << 2) | quad) ^ ((lq >> 1) & 7)) * 8;

  auto issue = [&](char* buf, int k0) {
    ld_lds16(buf + wave * 1024,               ag + k0);
    ld_lds16(buf + 4096 + wave * 2048,        bg + k0);
    ld_lds16(buf + 4096 + wave * 2048 + 1024, bg + k0 + 16 * DIM);
  };

  f32x4 acc[2][4];
#pragma unroll
  for (int i = 0; i < 2; ++i)
#pragma unroll
    for (int j = 0; j < 4; ++j) acc[i][j] = (f32x4){0.f, 0.f, 0.f, 0.f};

  char* bufA = smem;
  char* bufB = smem + 12288;
  issue(bufA, 0);
  __syncthreads();
  for (int k0 = 0; k0 < DIM; k0 += 32) {
    char* cur = ((k0 >> 5) & 1) ? bufB : bufA;
    char* nxt = ((k0 >> 5) & 1) ? bufA : bufB;
    if (k0 + 32 < DIM) issue(nxt, k0 + 32);
    const _Float16* Ahs = (const _Float16*)cur;
    const _Float16* Bhs = (const _Float16*)(cur + 4096);
    half8 ah[2];
#pragma unroll
    for (int i = 0; i < 2; ++i) {
      const int row = wm + i * 16 + lq;
      ah[i] = *(const half8*)&Ahs[(row >> 1) * 64 + swzB];
    }
#pragma unroll
    for (int j = 0; j < 4; ++j) {
      const int row = wn + j * 16 + lq;
      half8 bh = *(const half8*)&Bhs[(row >> 1) * 64 + swzB];
#pragma unroll
      for (int i = 0; i < 2; ++i) acc[i][j] = MFMA_F16K32(ah[i], bh, acc[i][j]);
    }
    __syncthreads();
  }
#pragma unroll
  for (int i = 0; i < 2; ++i)
#pragma unroll
    for (int j = 0; j < 4; ++j) {
      const int col = bn + wn + j * 16 + lq;
#pragma unroll
      for (int r = 0; r < 4; ++r) {
        const int row = bm + wm + i * 16 + quad * 4 + r;
        C[(size_t)row * 1024 + col] = acc[i][j][r];
      }
    }
}

// ---------------------------------------------------------------------------
extern "C" void kernel_launch(void* const* d_in, const int* in_sizes, int n_in,
                              void* d_out, int out_size, void* d_ws,
                              size_t ws_size, hipStream_t stream) {
  const float* x     = (const float*)d_in[0];
  const float* w_q   = (const float*)d_in[1];
  const float* w_vk  = (const float*)d_in[2];
  const float* w_out = (const float*)d_in[3];
  float* out = (float*)d_out;

  char* w = (char*)d_ws;  // 61 MB used
  __bf16*   wTh = (__bf16*)(w);                   // [3072][1024] 6MB
  __bf16*   wTl = (__bf16*)(w + (6ull << 20));    // [2048][1024] 4MB
  _Float16* woT = (_Float16*)(w + (10ull << 20)); // [1024][1024] 2MB
  __bf16*   qTh = (__bf16*)(w + (12ull << 20));   // [1024][4096] 8MB each
  __bf16*   qTl = (__bf16*)(w + (20ull << 20));
  __bf16*   khb = (__bf16*)(w + (28ull << 20));   // [4096][1024]
  __bf16*   klb = (__bf16*)(w + (36ull << 20));
  _Float16* vTb = (_Float16*)(w + (44ull << 20)); // [b][h][64][2048]
  _Float16* hob = (_Float16*)(w + (52ull << 20)); // [4096][1024]
  float2*   mlb = (float2*)(w + (60ull << 20));   // [2][32][2048] 1MB

  // d_out is scratch until gemm_out: xh/xl during prep/proj, partials after.
  __bf16* xh = (__bf16*)d_out;
  __bf16* xl = xh + (size_t)MROWS * DIM;
  _Float16* pO = (_Float16*)d_out;  // [2][32][2048][64] f16 = 16.78 MB exact

  dim3 blk(256);
  prep<<<dim3(3072), blk, 0, stream>>>(w_q, w_vk, w_out, x, wTh, wTl, woT, xh, xl);
  proj4<<<dim3(24, 32), blk, 0, stream>>>(
      xh, xl, wTh, wTl, qTh, qTl, khb, klb, vTb);
  attn6<<<dim3(16, 32, 2), blk, 0, stream>>>(qTh, qTl, khb, klb, vTb, pO, mlb);
  combine<<<dim3(2048), blk, 0, stream>>>(pO, mlb, hob);
  gemm_out<<<dim3(8, 64), blk, 0, stream>>>(hob, woT, out);
}

// Round 8
// 186.431 us; speedup vs baseline: 1.4643x; 1.4643x over previous
//
#include <hip/hip_runtime.h>

typedef _Float16 half4 __attribute__((ext_vector_type(4)));
typedef _Float16 half8 __attribute__((ext_vector_type(8)));
typedef float f32x4 __attribute__((ext_vector_type(4)));

#define MFMA_F16K32(a, b, c) __builtin_amdgcn_mfma_f32_16x16x32_f16(a, b, c, 0, 0, 0)
#define MFMA_F16K16(a, b, c) __builtin_amdgcn_mfma_f32_16x16x16f16(a, b, c, 0, 0, 0)
#define EXP2F(x) __builtin_amdgcn_exp2f(x)

constexpr int NSEQ = 2048, DIM = 1024;
constexpr int MROWS = 4096;
constexpr float QSCALE = 11.5415603271f;  // 8 * log2(e): logits in log2 units

__device__ __forceinline__ void ld_lds16(void* lds, const void* g) {
  __builtin_amdgcn_global_load_lds(
      (const __attribute__((address_space(1))) void*)g,
      (__attribute__((address_space(3))) void*)lds, 16, 0, 0);
}

// ---------------------------------------------------------------------------
// prep: blocks 0..1023 transpose weights 64x64 -> fp16 WT[3072][1024] / WoT;
// blocks 1024..3071: x -> fp16.
// ---------------------------------------------------------------------------
__global__ __launch_bounds__(256) void prep(
    const float* __restrict__ w_q, const float* __restrict__ w_vk,
    const float* __restrict__ w_out, const float* __restrict__ x,
    _Float16* __restrict__ WT, _Float16* __restrict__ WoT,
    _Float16* __restrict__ xf) {
  const int bid = blockIdx.x;
  const int t = threadIdx.x;
  if (bid >= 1024) {  // ---- x -> fp16 ----
    const size_t i = ((size_t)(bid - 1024) * 256 + t) * 8;
    float4 a = *(const float4*)(x + i), b2 = *(const float4*)(x + i + 4);
    float v[8] = {a.x, a.y, a.z, a.w, b2.x, b2.y, b2.z, b2.w};
    half8 h;
#pragma unroll
    for (int j = 0; j < 8; ++j) h[j] = (_Float16)v[j];
    *(half8*)(xf + i) = h;
    return;
  }
  __shared__ float T[64][65];
  const int bx = bid & 63, k0 = (bid >> 6) * 64;
  const float* src;
  int srcN, n0, dstrow, mode;
  float scale;
  if (bx < 16) {
    src = w_q; srcN = 1024; n0 = bx * 64; dstrow = n0; scale = QSCALE; mode = 0;
  } else if (bx < 48) {
    src = w_vk; srcN = 2048; n0 = (bx - 16) * 64; dstrow = 1024 + n0;
    scale = 1.0f; mode = 0;
  } else {
    src = w_out; srcN = 1024; n0 = (bx - 48) * 64; dstrow = n0;
    scale = 1.0f; mode = 1;
  }
  {
    const int r = t >> 2, c4 = (t & 3) * 16;
    const float* s = src + (size_t)(k0 + r) * srcN + n0 + c4;
    float4 v0 = ((const float4*)s)[0], v1 = ((const float4*)s)[1],
           v2 = ((const float4*)s)[2], v3 = ((const float4*)s)[3];
    *(float4*)&T[r][c4 + 0] = v0;  *(float4*)&T[r][c4 + 4] = v1;
    *(float4*)&T[r][c4 + 8] = v2;  *(float4*)&T[r][c4 + 12] = v3;
  }
  __syncthreads();
  const int rn = t >> 2, kc = (t & 3) * 16;
  half8 hv[2];
#pragma unroll
  for (int half = 0; half < 2; ++half)
#pragma unroll
    for (int j = 0; j < 8; ++j)
      hv[half][j] = (_Float16)(T[kc + half * 8 + j][rn] * scale);
  _Float16* d = ((mode == 0) ? WT + (size_t)(dstrow + rn) * 1024
                             : WoT + (size_t)(n0 + rn) * 1024) + k0 + kc;
  *(half8*)d = hv[0]; *(half8*)(d + 8) = hv[1];
}

// ---------------------------------------------------------------------------
// Fused q/k/v projection, all fp16 single-product. 128x128 tile, BK=32,
// double-buffered 2x16KB, ONE barrier per K-iter, 3 blocks/CU.
// kind = bn>>10: 0 -> qb [tok][1024] (weights pre-scaled by QSCALE);
// 1 -> kb [tok][1024]; 2 -> vT fp16 [b][h][d][n].
// ---------------------------------------------------------------------------
__global__ __launch_bounds__(256, 3) void proj6(
    const _Float16* __restrict__ xf, const _Float16* __restrict__ WT,
    _Float16* __restrict__ qb, _Float16* __restrict__ kb,
    _Float16* __restrict__ VT) {
  __shared__ __align__(16) char smem[32768];  // 2 bufs x (X 8KB | B 8KB)
  const int t = threadIdx.x;
  const int lane = t & 63, wave = t >> 6, quad = lane >> 4, lq = lane & 15;
  const int bn = blockIdx.x * 128, bm = blockIdx.y * 128;
  const int kind = bn >> 10;
  const int wm = (wave >> 1) * 64, wn = (wave & 1) * 64;

  // staging: 64B rows (32 fp16); one 1KB issue = 16 rows, 4 lanes/row.
  const int srow = lane >> 2;                // 0..15
  const int schk = (lane & 3) ^ (srow & 3);  // 16B chunk
  const _Float16* xg = xf + (size_t)(bm + wave * 32 + srow) * DIM + schk * 8;
  const _Float16* bg = WT + (size_t)(bn + wave * 32 + srow) * DIM + schk * 8;
  const int wb = wave * 2048;  // 32 rows x 64B

  auto issue = [&](char* buf, int k0) {
    ld_lds16(buf + wb,                xg + k0);
    ld_lds16(buf + wb + 1024,         xg + k0 + 16 * DIM);
    ld_lds16(buf + 8192 + wb,         bg + k0);
    ld_lds16(buf + 8192 + wb + 1024,  bg + k0 + 16 * DIM);
  };

  const int swz = (quad ^ (lq & 3)) * 8;  // chunk c of row r at c^(r&3)

  f32x4 acc[4][4];
#pragma unroll
  for (int i = 0; i < 4; ++i)
#pragma unroll
    for (int j = 0; j < 4; ++j) acc[i][j] = (f32x4){0.f, 0.f, 0.f, 0.f};

  char* bufA = smem;
  char* bufB = smem + 16384;
  issue(bufA, 0);
  for (int k0 = 0; k0 < DIM; k0 += 32) {
    char* cur = ((k0 >> 5) & 1) ? bufB : bufA;
    char* nxt = ((k0 >> 5) & 1) ? bufA : bufB;
    __syncthreads();  // drain DMA for cur; all waves done reading nxt
    if (k0 + 32 < DIM) issue(nxt, k0 + 32);
    const _Float16* Xs = (const _Float16*)cur;
    const _Float16* Bs = (const _Float16*)(cur + 8192);
    half8 ah[4];
#pragma unroll
    for (int i = 0; i < 4; ++i)
      ah[i] = *(const half8*)&Xs[(wm + i * 16 + lq) * 32 + swz];
#pragma unroll
    for (int j = 0; j < 4; ++j) {
      half8 bf = *(const half8*)&Bs[(wn + j * 16 + lq) * 32 + swz];
#pragma unroll
      for (int i = 0; i < 4; ++i) acc[i][j] = MFMA_F16K32(ah[i], bf, acc[i][j]);
    }
  }

  if (kind == 2) {  // v -> vT[b][h][d][n], 4 consecutive tokens / 8B store
#pragma unroll
    for (int i = 0; i < 4; ++i)
#pragma unroll
      for (int j = 0; j < 4; ++j) {
        const int c = (bn - 2048) + wn + j * 16 + lq;  // h*64 + d
        const int row0 = bm + wm + i * 16 + quad * 4;  // token
        const int b = row0 >> 11, n = row0 & 2047;
        const int h = c >> 6, d = c & 63;
        half4 o;
#pragma unroll
        for (int r = 0; r < 4; ++r) o[r] = (_Float16)acc[i][j][r];
        *(half4*)(VT + ((size_t)(b * 16 + h) * 64 + d) * 2048 + n) = o;
      }
  } else {
    _Float16* D = (kind == 0) ? qb : kb;
    const int cb = bn & 1023;
#pragma unroll
    for (int i = 0; i < 4; ++i)
#pragma unroll
      for (int j = 0; j < 4; ++j) {
        const int col = cb + wn + j * 16 + lq;
#pragma unroll
        for (int r = 0; r < 4; ++r) {
          const int row = bm + wm + i * 16 + quad * 4 + r;
          D[(size_t)row * 1024 + col] = (_Float16)acc[i][j][r];
        }
      }
  }
}

// ---------------------------------------------------------------------------
// Flash attention, all fp16 single-product. TI=128 (4 waves x 32 q-rows),
// TJ=128, double-buffered 2x32KB DMA staging, ONE barrier per 128-key iter.
// S^T = K.Q^T (f16 K32); softmax in regs (exp2); O^T = V^T.P^T (f16 K16,
// P^T direct from C-layout regs). Q pinned in registers (contiguous loads).
// ---------------------------------------------------------------------------
__global__ __launch_bounds__(256, 2) void attn7(
    const _Float16* __restrict__ qb, const _Float16* __restrict__ kb,
    const _Float16* __restrict__ vT, _Float16* __restrict__ ho) {
  __shared__ __align__(16) char smem[65536];  // 2 bufs: K 16KB | V 16KB
  const int t = threadIdx.x;
  const int lane = t & 63, wave = t >> 6, quad = lane >> 4, lq = lane & 15;
  const int i0 = blockIdx.x * 128;
  const int bh = blockIdx.y, b = bh >> 4, head = bh & 15;
  const size_t rowbase = (size_t)b * NSEQ;

  // Q fragments (B-operand layout), contiguous 16B loads
  half8 qf[2][2];
#pragma unroll
  for (int qt = 0; qt < 2; ++qt) {
    const _Float16* qp =
        qb + (rowbase + i0 + wave * 32 + qt * 16 + lq) * DIM + head * 64 + quad * 8;
    qf[qt][0] = *(const half8*)qp;
    qf[qt][1] = *(const half8*)(qp + 32);
  }

  f32x4 o[2][4];
#pragma unroll
  for (int qt = 0; qt < 2; ++qt)
#pragma unroll
    for (int dt = 0; dt < 4; ++dt) o[qt][dt] = (f32x4){0.f, 0.f, 0.f, 0.f};
  float mrun[2] = {-3.0e38f, -3.0e38f};
  float lrun[2] = {0.f, 0.f};

  // K staging: 128 rows x 128B; wave stages rows wave*32..+31 (4 issues).
  const int srow = lane >> 3, schk = (lane & 7) ^ srow;
  const _Float16* kg =
      kb + (rowbase + wave * 32 + srow) * DIM + head * 64 + schk * 8;
  // V staging: 64 d-rows x 256B; wave stages rows wave*16..+15 (4 issues).
  int vco[4];
#pragma unroll
  for (int is = 0; is < 4; ++is)
    vco[is] = ((lane & 15) ^ (is * 4 + (lane >> 4))) * 8;
  const _Float16* vg = vT + ((size_t)bh * 64 + wave * 16 + (lane >> 4)) * NSEQ;

  auto issue = [&](char* buf, int j0) {
#pragma unroll
    for (int is = 0; is < 4; ++is) {
      ld_lds16(buf + wave * 4096 + is * 1024,
               kg + ((size_t)j0 + is * 8) * DIM);
      ld_lds16(buf + 16384 + (wave * 16 + is * 4) * 256,
               vg + (size_t)is * 4 * NSEQ + j0 + vco[is]);
    }
  };

  const int swzK0 = (quad ^ (lq & 7)) * 8;        // chunk c of row r at c^(r&7)
  const int swzK1 = ((quad + 4) ^ (lq & 7)) * 8;

  char* bufA = smem;
  char* bufB = smem + 32768;
  issue(bufA, 0);

  for (int j0 = 0; j0 < NSEQ; j0 += 128) {
    char* cur = ((j0 >> 7) & 1) ? bufB : bufA;
    char* nxt = ((j0 >> 7) & 1) ? bufA : bufB;
    __syncthreads();  // drain cur's DMA; all waves done reading nxt
    if (j0 + 128 < NSEQ) issue(nxt, j0 + 128);
    const _Float16* Khs = (const _Float16*)cur;          // [128][64 elems]
    const _Float16* Vts = (const _Float16*)(cur + 16384);  // [64][128 elems]

#pragma unroll
    for (int jh = 0; jh < 2; ++jh) {
      // S^T = K.Q^T (single f16 product)
      f32x4 s[2][4];
#pragma unroll
      for (int nt = 0; nt < 4; ++nt) {
        const int roff = (jh * 64 + nt * 16 + lq) * 64;
        half8 k0f = *(const half8*)&Khs[roff + swzK0];
        half8 k1f = *(const half8*)&Khs[roff + swzK1];
#pragma unroll
        for (int qt = 0; qt < 2; ++qt) {
          f32x4 sv = (f32x4){0.f, 0.f, 0.f, 0.f};
          sv = MFMA_F16K32(k0f, qf[qt][0], sv);
          sv = MFMA_F16K32(k1f, qf[qt][1], sv);
          s[qt][nt] = sv;
        }
      }
      // online softmax: q-rows lane-resident; 2 shuffles per reduction
      half4 pb[2][4];
#pragma unroll
      for (int qt = 0; qt < 2; ++qt) {
        float mx = s[qt][0][0];
#pragma unroll
        for (int nt = 0; nt < 4; ++nt)
#pragma unroll
          for (int r = 0; r < 4; ++r) mx = fmaxf(mx, s[qt][nt][r]);
        mx = fmaxf(mx, __shfl_xor(mx, 16));
        mx = fmaxf(mx, __shfl_xor(mx, 32));
        const float mn = fmaxf(mrun[qt], mx);
        const float alpha = EXP2F(mrun[qt] - mn);
        mrun[qt] = mn;
        float rs = 0.f;
#pragma unroll
        for (int nt = 0; nt < 4; ++nt)
#pragma unroll
          for (int r = 0; r < 4; ++r) {
            float p = EXP2F(s[qt][nt][r] - mn);
            rs += p;
            pb[qt][nt][r] = (_Float16)p;
          }
        rs += __shfl_xor(rs, 16);
        rs += __shfl_xor(rs, 32);
        lrun[qt] = lrun[qt] * alpha + rs;
#pragma unroll
        for (int dt = 0; dt < 4; ++dt) o[qt][dt] *= alpha;
      }
      // O^T += V^T . P^T  (P^T straight from C-layout registers)
#pragma unroll
      for (int dt = 0; dt < 4; ++dt) {
        const int vrow = (dt * 16 + lq) * 128;
#pragma unroll
        for (int nt = 0; nt < 4; ++nt) {
          const int ntj = jh * 4 + nt;
          const int voff =
              vrow + ((2 * ntj + (quad >> 1)) ^ lq) * 8 + (quad & 1) * 4;
          half4 va = *(const half4*)&Vts[voff];
          o[0][dt] = MFMA_F16K16(va, pb[0][nt], o[0][dt]);
          o[1][dt] = MFMA_F16K16(va, pb[1][nt], o[1][dt]);
        }
      }
    }
  }

  // epilogue: O^T -> LDS transpose (pitch 80 f16, in bufA) -> coalesced store
  _Float16* Ots = (_Float16*)smem;
  __syncthreads();  // all waves done with final tile reads
#pragma unroll
  for (int qt = 0; qt < 2; ++qt) {
    const float inv = 1.0f / lrun[qt];
#pragma unroll
    for (int dt = 0; dt < 4; ++dt)
#pragma unroll
      for (int r = 0; r < 4; ++r)
        Ots[(wave * 32 + qt * 16 + lq) * 80 + dt * 16 + quad * 4 + r] =
            (_Float16)(o[qt][dt][r] * inv);
  }
  __syncthreads();
  {
    const int row = t >> 1, hf = t & 1;
    const _Float16* src = &Ots[row * 80 + hf * 32];
    half8 o0 = ((const half8*)src)[0], o1 = ((const half8*)src)[1],
          o2 = ((const half8*)src)[2], o3 = ((const half8*)src)[3];
    _Float16* dst = ho + (rowbase + i0 + row) * DIM + head * 64 + hf * 32;
    ((half8*)dst)[0] = o0; ((half8*)dst)[1] = o1;
    ((half8*)dst)[2] = o2; ((half8*)dst)[3] = o3;
  }
}

// ---------------------------------------------------------------------------
// out = ho(fp16) @ w_out — double-buffered, one barrier per K-iter.
// ---------------------------------------------------------------------------
__global__ __launch_bounds__(256, 4) void gemm_out(
    const _Float16* __restrict__ A, const _Float16* __restrict__ BT,
    float* __restrict__ C) {
  __shared__ __align__(16) char smem[24576];  // 2 bufs: A 4KB | B 8KB
  const int t = threadIdx.x;
  const int lane = t & 63, wave = t >> 6, quad = lane >> 4, lq = lane & 15;
  const int bn = blockIdx.x * 128, bm = blockIdx.y * 64;
  const int wm = (wave >> 1) * 32, wn = (wave & 1) * 64;

  const int bco = (lane & 7) ^ (lane >> 3);
  const int brow = 2 * (lane >> 3) + (bco >> 2);
  const int bcc = bco & 3;
  const _Float16* ag = A + (size_t)(bm + wave * 16 + brow) * DIM + bcc * 8;
  const _Float16* bg = BT + (size_t)(bn + wave * 32 + brow) * DIM + bcc * 8;
  const int swzB = ((((lq & 1) << 2) | quad) ^ ((lq >> 1) & 7)) * 8;

  auto issue = [&](char* buf, int k0) {
    ld_lds16(buf + wave * 1024,               ag + k0);
    ld_lds16(buf + 4096 + wave * 2048,        bg + k0);
    ld_lds16(buf + 4096 + wave * 2048 + 1024, bg + k0 + 16 * DIM);
  };

  f32x4 acc[2][4];
#pragma unroll
  for (int i = 0; i < 2; ++i)
#pragma unroll
    for (int j = 0; j < 4; ++j) acc[i][j] = (f32x4){0.f, 0.f, 0.f, 0.f};

  char* bufA = smem;
  char* bufB = smem + 12288;
  issue(bufA, 0);
  for (int k0 = 0; k0 < DIM; k0 += 32) {
    char* cur = ((k0 >> 5) & 1) ? bufB : bufA;
    char* nxt = ((k0 >> 5) & 1) ? bufA : bufB;
    __syncthreads();
    if (k0 + 32 < DIM) issue(nxt, k0 + 32);
    const _Float16* Ahs = (const _Float16*)cur;
    const _Float16* Bhs = (const _Float16*)(cur + 4096);
    half8 ah[2];
#pragma unroll
    for (int i = 0; i < 2; ++i) {
      const int row = wm + i * 16 + lq;
      ah[i] = *(const half8*)&Ahs[(row >> 1) * 64 + swzB];
    }
#pragma unroll
    for (int j = 0; j < 4; ++j) {
      const int row = wn + j * 16 + lq;
      half8 bf = *(const half8*)&Bhs[(row >> 1) * 64 + swzB];
#pragma unroll
      for (int i = 0; i < 2; ++i) acc[i][j] = MFMA_F16K32(ah[i], bf, acc[i][j]);
    }
  }
#pragma unroll
  for (int i = 0; i < 2; ++i)
#pragma unroll
    for (int j = 0; j < 4; ++j) {
      const int col = bn + wn + j * 16 + lq;
#pragma unroll
      for (int r = 0; r < 4; ++r) {
        const int row = bm + wm + i * 16 + quad * 4 + r;
        C[(size_t)row * 1024 + col] = acc[i][j][r];
      }
    }
}

// ---------------------------------------------------------------------------
extern "C" void kernel_launch(void* const* d_in, const int* in_sizes, int n_in,
                              void* d_out, int out_size, void* d_ws,
                              size_t ws_size, hipStream_t stream) {
  const float* x     = (const float*)d_in[0];
  const float* w_q   = (const float*)d_in[1];
  const float* w_vk  = (const float*)d_in[2];
  const float* w_out = (const float*)d_in[3];
  float* out = (float*)d_out;

  char* w = (char*)d_ws;  // 48 MB used
  _Float16* wT  = (_Float16*)(w);                  // [3072][1024] 6MB
  _Float16* woT = (_Float16*)(w + (6ull << 20));   // [1024][1024] 2MB
  _Float16* qbb = (_Float16*)(w + (8ull << 20));   // [4096][1024] 8MB
  _Float16* kbb = (_Float16*)(w + (16ull << 20));  // [4096][1024] 8MB
  _Float16* vTb = (_Float16*)(w + (24ull << 20));  // [b][h][64][2048] 8MB
  _Float16* hob = (_Float16*)(w + (32ull << 20));  // [4096][1024] 8MB
  _Float16* xfb = (_Float16*)(w + (40ull << 20));  // [4096][1024] 8MB

  dim3 blk(256);
  prep<<<dim3(3072), blk, 0, stream>>>(w_q, w_vk, w_out, x, wT, woT, xfb);
  proj6<<<dim3(24, 32), blk, 0, stream>>>(xfb, wT, qbb, kbb, vTb);
  attn7<<<dim3(16, 32), blk, 0, stream>>>(qbb, kbb, vTb, hob);
  gemm_out<<<dim3(8, 64), blk, 0, stream>>>(hob, woT, out);
}